// Round 5
// baseline (637.811 us; speedup 1.0000x reference)
//
#include <hip/hip_runtime.h>
#include <hip/hip_fp16.h>

// Problem constants
#define OUT_F 4096
#define IN_F  4096
#define M_TOTAL 8192          // 4 * 2048
#define TOTAL_W (OUT_F * IN_F)

typedef _Float16 f16x8 __attribute__((ext_vector_type(8)));
typedef float    f32x4 __attribute__((ext_vector_type(4)));

__device__ const float NF4_LUT_C[16] = {
    -1.0f, -0.6961928009986877f, -0.5250730514526367f, -0.39491748809814453f,
    -0.28444138169288635f, -0.18477343022823334f, -0.09105003625154495f, 0.0f,
    0.07958029955625534f, 0.16093020141124725f, 0.24611230194568634f,
    0.33791524171829224f, 0.44070982933044434f, 0.5626170039176941f,
    0.7229568362236023f, 1.0f};

// ---------------- Fused prep: dequant (blocks 0..8191) + cast (8192..24575) ----
#define DEQ_BLOCKS (TOTAL_W / 8 / 256)                  // 8192
#define CAST_BLOCKS ((size_t)M_TOTAL * IN_F / 8 / 256)  // 16384

__global__ __launch_bounds__(256) void k_prep(const int* __restrict__ idx,
                                              const int* __restrict__ qs,
                                              _Float16* __restrict__ W,
                                              const float* __restrict__ x,
                                              _Float16* __restrict__ xh) {
    // 32 replicated LUT copies, lane pair (l>>1) owns copy c -> ~2-way random
    __shared__ float slut[32][16];
    for (int i = threadIdx.x; i < 512; i += 256) slut[i >> 4][i & 15] = NF4_LUT_C[i & 15];
    __syncthreads();
    if (blockIdx.x < DEQ_BLOCKS) {
        const float* myl = slut[(threadIdx.x & 63) >> 1];
        int t = blockIdx.x * 256 + threadIdx.x;          // 0 .. TOTAL_W/8-1
        const int4* ip = (const int4*)idx;
        int4 a = ip[2 * t];
        int4 b = ip[2 * t + 1];
        // exact reference order: (q/127)*0.05 in fp32, then vals*absmax, fp16 cast
        float absmax = ((float)qs[t >> 3] / 127.0f) * 0.05f;
        f16x8 o;
        o[0] = (_Float16)(myl[a.x] * absmax);
        o[1] = (_Float16)(myl[a.y] * absmax);
        o[2] = (_Float16)(myl[a.z] * absmax);
        o[3] = (_Float16)(myl[a.w] * absmax);
        o[4] = (_Float16)(myl[b.x] * absmax);
        o[5] = (_Float16)(myl[b.y] * absmax);
        o[6] = (_Float16)(myl[b.z] * absmax);
        o[7] = (_Float16)(myl[b.w] * absmax);
        *(f16x8*)(W + (size_t)t * 8) = o;
    } else {
        size_t t = (size_t)(blockIdx.x - DEQ_BLOCKS) * 256 + threadIdx.x;
        const float4* xp = (const float4*)x;
        float4 a = xp[2 * t];
        float4 b = xp[2 * t + 1];
        f16x8 o;
        o[0] = (_Float16)a.x; o[1] = (_Float16)a.y; o[2] = (_Float16)a.z; o[3] = (_Float16)a.w;
        o[4] = (_Float16)b.x; o[5] = (_Float16)b.y; o[6] = (_Float16)b.z; o[7] = (_Float16)b.w;
        *(f16x8*)(xh + t * 8) = o;
    }
}

// ---------------- GEMM: C[M][N] = A[M][K] * B[N][K]^T ----------------
// 256x256 tile, BK=64, 512 threads = 8 waves (2M x 4N), per-wave 128x64 via
// 8x4 frags of mfma_f32_16x16x32_f16. Geometry/swizzle/staging/epilogue are
// byte-identical to round-1 (measured: 0 conflicts). Schedule: one-phase-ahead
// ds_reads with counted lgkm, 2 barriers/tile, ~1-tile vmcnt prefetch distance.
//
// Steady-state tile t (C1=A03xB01, C2=A03xB23, C3=A47xB01, C4=A47xB23):
//  ph1: issue rdA47(t)[8]; lgkm(8) [retires A03(t),B01(t),B23(t)]; C1
//  ph2: C2                                   (pure MFMA, no mem waits)
//  ph3: vmcnt(0) [queue = STAGE(t+1): B issued ph3 of t-1 (4 phases ago),
//                 A issued ph4 of t-1 (3 phases ago) -> latency covered];
//       BAR [t+1 LDS-visible to all waves; also: every wave passed its ph1
//            lgkm(8) -> ALL B(t) reads retired -> sB[t&1] is dead];
//       STAGE_B(t+2) -> sB[t&1];
//       issue rdA03(t+1)[8]; lgkm(8) [retires A47(t)]; C3;
//       BAR [every wave retired all A(t) reads -> sA[t&1] dead]
//  ph4: STAGE_A(t+2) -> sA[t&1]; issue rdB01(t+1)[4]; C4 (uses bf23(t));
//       issue rdB23(t+1)[4]
//  Next ph1's lgkm(8) retires A03+B01+B23 of t+1 exactly (in-order DS retire).
// Stage safety is barrier-proven (no reliance on wave-timing margins); MFMA
// operand correctness is compiler-guaranteed (loads are visible to its
// auto-waitcnt) -- manual counts are schedule hints only.
//
// Swizzle (proven 0-conflict): 16B chunk (row r, pos c) at physical r*8+(c^(r&7));
// staging pre-swizzles the GLOBAL k-offset, LDS dest stays lane-linear; reads
// use pos=((ks*4+fk)^(fr&7))*8 -> each 8-lane group covers all 8 slots.

__device__ __forceinline__ void async16(const _Float16* g, _Float16* l) {
    __builtin_amdgcn_global_load_lds(
        (const __attribute__((address_space(1))) void*)g,
        (__attribute__((address_space(3))) void*)l,
        16, 0, 0);
}

#define MFMA16(a, b, c) __builtin_amdgcn_mfma_f32_16x16x32_f16(a, b, c, 0, 0, 0)
#define BAR()    __builtin_amdgcn_s_barrier()
#define VMCNT(n) asm volatile("s_waitcnt vmcnt(" #n ")" ::: "memory")
#define LGKM(n)  asm volatile("s_waitcnt lgkmcnt(" #n ")" ::: "memory")
#define PRIO(n)  __builtin_amdgcn_s_setprio(n)

#define TILE_E (256 * 64)     // 16384 elems = 32 KiB
#define NT (IN_F / 64)        // 64

__global__ __launch_bounds__(512, 2) void k_gemm(const _Float16* __restrict__ A,
                                                 const _Float16* __restrict__ B,
                                                 float* __restrict__ C) {
    const int K = IN_F, N = OUT_F;
    __shared__ __align__(1024) _Float16 sAm[2 * TILE_E];   // 64 KiB
    __shared__ __align__(1024) _Float16 sBm[2 * TILE_E];   // 64 KiB
    _Float16* sA0 = &sAm[0];
    _Float16* sB0 = &sBm[0];

    const int tid = threadIdx.x;
    // Raster: 32 groups of 16 blocks (4 bm x 4 bn) over 32x16 tile grid.
    const int bid = blockIdx.x;            // 0..511
    const int g   = bid >> 4;              // 0..31
    const int wv  = bid & 15;
    const int gy  = g >> 2;                // 0..7
    const int gx  = g & 3;                 // 0..3
    const int m0  = (gy * 4 + (wv >> 2)) * 256;
    const int n0  = (gx * 4 + (wv & 3)) * 256;

    const int lane = tid & 63;
    const int wave = tid >> 6;
    const int wm   = (wave >> 2) * 128;    // 0 or 128
    const int wn   = (wave & 3) * 64;      // 0,64,128,192

    // 16x16x32 fragment addressing: row/col = lane&15, k-chunk = lane>>4
    const int fr   = lane & 15;
    const int fk   = lane >> 4;
    const int sw   = fr & 7;
    const int aRow = (wm + fr) * 64;       // element offset of frag row base
    const int bRow = (wn + fr) * 64;
    const int p0   = ((0 * 4 + fk) ^ sw) * 8;   // kstep 0 phys offset (elems)
    const int p1   = ((1 * 4 + fk) ^ sw) * 8;   // kstep 1
    const int aAd0 = aRow + p0, aAd1 = aRow + p1;
    const int bAd0 = bRow + p0, bAd1 = bRow + p1;

    // Staging: thread t, pass j fills phys chunk j*512+t: row = j*64 + (t>>3),
    // pos = t&7, global kchunk = pos ^ (row&7) = (t&7)^((t>>3)&7) (j-invariant).
    const int rr  = tid >> 3;                              // 0..63
    const int kc  = ((tid & 7) ^ (rr & 7)) * 8;            // global k elem offset
    const _Float16* agp = A + (size_t)(m0 + rr) * K + kc;
    const _Float16* bgp = B + (size_t)(n0 + rr) * K + kc;
    const int dOff = tid * 8;                              // LDS dest elem offset

#define STAGE_A(T) do {                                                       \
        _Float16* da_ = sA0 + ((T) & 1) * TILE_E + dOff;                      \
        const size_t ko_ = (size_t)(T) * 64;                                  \
        async16(agp + ko_,                   da_);                            \
        async16(agp + ko_ + (size_t)64 * K,  da_ + 4096);                     \
        async16(agp + ko_ + (size_t)128 * K, da_ + 8192);                     \
        async16(agp + ko_ + (size_t)192 * K, da_ + 12288);                    \
    } while (0)
#define STAGE_B(T) do {                                                       \
        _Float16* db_ = sB0 + ((T) & 1) * TILE_E + dOff;                      \
        const size_t ko_ = (size_t)(T) * 64;                                  \
        async16(bgp + ko_,                   db_);                            \
        async16(bgp + ko_ + (size_t)64 * K,  db_ + 4096);                     \
        async16(bgp + ko_ + (size_t)128 * K, db_ + 8192);                     \
        async16(bgp + ko_ + (size_t)192 * K, db_ + 12288);                    \
    } while (0)

    // Fragment registers
    f16x8 a03[4][2], a47[4][2], bf[4][2];

#define RD_A03(T) do {                                                        \
        const _Float16* p_ = sA0 + ((T) & 1) * TILE_E;                        \
        _Pragma("unroll")                                                     \
        for (int mi = 0; mi < 4; ++mi) {                                      \
            a03[mi][0] = *(const f16x8*)(p_ + aAd0 + mi * 1024);              \
            a03[mi][1] = *(const f16x8*)(p_ + aAd1 + mi * 1024);              \
        }                                                                     \
    } while (0)
#define RD_A47(T) do {                                                        \
        const _Float16* p_ = sA0 + ((T) & 1) * TILE_E + 4096;                 \
        _Pragma("unroll")                                                     \
        for (int mi = 0; mi < 4; ++mi) {                                      \
            a47[mi][0] = *(const f16x8*)(p_ + aAd0 + mi * 1024);              \
            a47[mi][1] = *(const f16x8*)(p_ + aAd1 + mi * 1024);              \
        }                                                                     \
    } while (0)
#define RD_B01(T) do {                                                        \
        const _Float16* p_ = sB0 + ((T) & 1) * TILE_E;                        \
        _Pragma("unroll")                                                     \
        for (int ni = 0; ni < 2; ++ni) {                                      \
            bf[ni][0] = *(const f16x8*)(p_ + bAd0 + ni * 1024);               \
            bf[ni][1] = *(const f16x8*)(p_ + bAd1 + ni * 1024);               \
        }                                                                     \
    } while (0)
#define RD_B23(T) do {                                                        \
        const _Float16* p_ = sB0 + ((T) & 1) * TILE_E;                        \
        _Pragma("unroll")                                                     \
        for (int ni = 2; ni < 4; ++ni) {                                      \
            bf[ni][0] = *(const f16x8*)(p_ + bAd0 + ni * 1024);               \
            bf[ni][1] = *(const f16x8*)(p_ + bAd1 + ni * 1024);               \
        }                                                                     \
    } while (0)

    f32x4 acc[8][4];
#pragma unroll
    for (int mi = 0; mi < 8; ++mi)
#pragma unroll
        for (int ni = 0; ni < 4; ++ni)
#pragma unroll
            for (int r = 0; r < 4; ++r) acc[mi][ni][r] = 0.f;

    // 16-MFMA cluster: A-set x 2 B-columns, 8 independent acc chains
#define MMC(ASET, AB, NB) do {                                                \
        PRIO(1);                                                              \
        _Pragma("unroll")                                                     \
        for (int mi = 0; mi < 4; ++mi) {                                      \
            acc[AB + mi][NB + 0] =                                            \
                MFMA16(ASET[mi][0], bf[NB + 0][0], acc[AB + mi][NB + 0]);     \
            acc[AB + mi][NB + 1] =                                            \
                MFMA16(ASET[mi][0], bf[NB + 1][0], acc[AB + mi][NB + 1]);     \
        }                                                                     \
        _Pragma("unroll")                                                     \
        for (int mi = 0; mi < 4; ++mi) {                                      \
            acc[AB + mi][NB + 0] =                                            \
                MFMA16(ASET[mi][1], bf[NB + 0][1], acc[AB + mi][NB + 0]);     \
            acc[AB + mi][NB + 1] =                                            \
                MFMA16(ASET[mi][1], bf[NB + 1][1], acc[AB + mi][NB + 1]);     \
        }                                                                     \
        PRIO(0);                                                              \
    } while (0)

    // ---- prologue ----
    STAGE_B(0); STAGE_A(0); STAGE_B(1); STAGE_A(1);
    VMCNT(8);            // tile 0 landed; tile 1 (8 loads) in flight
    BAR();
    RD_A03(0); RD_B01(0); RD_B23(0);   // 16 ds_reads outstanding

#pragma unroll 2
    for (int t = 0; t < NT; ++t) {
        // ---------- phase 1 ----------
        RD_A47(t);                       // +8 -> 24 outstanding DS
        LGKM(8);                         // A03(t), B01(t), B23(t) retired
        MMC(a03, 0, 0);                  // C1 = A03 x B01
        // ---------- phase 2 ----------
        MMC(a03, 0, 2);                  // C2 = A03 x B23 (pure MFMA)
        // ---------- phase 3 ----------
        VMCNT(0);                        // STAGE(t+1): issued 3-4 phases ago
        BAR();                           // t+1 visible; all B(t) reads retired
        if (t + 2 < NT) STAGE_B(t + 2);  // -> sB[t&1], dead per BAR above
        if (t + 1 < NT) {
            RD_A03(t + 1);               // other buffer
            LGKM(8);                     // retires A47(t); A03(t+1) in flight
        } else {
            LGKM(0);                     // tail: just retire A47
        }
        MMC(a47, 4, 0);                  // C3 = A47 x B01
        BAR();                           // all waves retired ALL tile-t reads
        // ---------- phase 4 ----------
        if (t + 2 < NT) STAGE_A(t + 2);  // -> sA[t&1], dead per BAR above
        if (t + 1 < NT) RD_B01(t + 1);   // bf01 dead (C3 done); C4 uses bf23
        MMC(a47, 4, 2);                  // C4 = A47 x B23
        if (t + 1 < NT) RD_B23(t + 1);   // bf23 dead after C4
    }

    // Epilogue: 16x16x32 C/D layout col=lane&15, row=(lane>>4)*4+reg
    const int crow0 = m0 + wm + fk * 4;
    const int ccol0 = n0 + wn + fr;
#pragma unroll
    for (int mi = 0; mi < 8; ++mi)
#pragma unroll
        for (int ni = 0; ni < 4; ++ni)
#pragma unroll
            for (int r = 0; r < 4; ++r)
                C[(size_t)(crow0 + mi * 16 + r) * N + ccol0 + ni * 16] = acc[mi][ni][r];
}

extern "C" void kernel_launch(void* const* d_in, const int* in_sizes, int n_in,
                              void* d_out, int out_size, void* d_ws, size_t ws_size,
                              hipStream_t stream) {
    const float* x       = (const float*)d_in[0];
    const int*   indices = (const int*)d_in[1];
    const int*   qscales = (const int*)d_in[2];
    float*       out     = (float*)d_out;

    _Float16* W  = (_Float16*)d_ws;                                   // 32 MiB
    _Float16* Xh = (_Float16*)((char*)d_ws + (size_t)TOTAL_W * 2);    // 64 MiB

    k_prep<<<DEQ_BLOCKS + (int)CAST_BLOCKS, 256, 0, stream>>>(indices, qscales, W, x, Xh);
    k_gemm<<<512, 512, 0, stream>>>(Xh, W, out);
}

// Round 6
// 497.063 us; speedup vs baseline: 1.2832x; 1.2832x over previous
//
#include <hip/hip_runtime.h>
#include <hip/hip_fp16.h>

// Problem constants
#define OUT_F 4096
#define IN_F  4096
#define M_TOTAL 8192          // 4 * 2048
#define TOTAL_W (OUT_F * IN_F)

typedef _Float16 f16x8 __attribute__((ext_vector_type(8)));
typedef float    f32x16 __attribute__((ext_vector_type(16)));

__device__ const float NF4_LUT_C[16] = {
    -1.0f, -0.6961928009986877f, -0.5250730514526367f, -0.39491748809814453f,
    -0.28444138169288635f, -0.18477343022823334f, -0.09105003625154495f, 0.0f,
    0.07958029955625534f, 0.16093020141124725f, 0.24611230194568634f,
    0.33791524171829224f, 0.44070982933044434f, 0.5626170039176941f,
    0.7229568362236023f, 1.0f};

// ---------------- Fused prep: dequant (blocks 0..8191) + cast (8192..24575) ----
#define DEQ_BLOCKS (TOTAL_W / 8 / 256)                  // 8192
#define CAST_BLOCKS ((size_t)M_TOTAL * IN_F / 8 / 256)  // 16384

__global__ __launch_bounds__(256) void k_prep(const int* __restrict__ idx,
                                              const int* __restrict__ qs,
                                              _Float16* __restrict__ W,
                                              const float* __restrict__ x,
                                              _Float16* __restrict__ xh) {
    // 32 replicated LUT copies, lane pair (l>>1) owns copy c -> ~2-way random
    __shared__ float slut[32][16];
    for (int i = threadIdx.x; i < 512; i += 256) slut[i >> 4][i & 15] = NF4_LUT_C[i & 15];
    __syncthreads();
    if (blockIdx.x < DEQ_BLOCKS) {
        const float* myl = slut[(threadIdx.x & 63) >> 1];
        int t = blockIdx.x * 256 + threadIdx.x;          // 0 .. TOTAL_W/8-1
        const int4* ip = (const int4*)idx;
        int4 a = ip[2 * t];
        int4 b = ip[2 * t + 1];
        // exact reference order: (q/127)*0.05 in fp32, then vals*absmax, fp16 cast
        float absmax = ((float)qs[t >> 3] / 127.0f) * 0.05f;
        f16x8 o;
        o[0] = (_Float16)(myl[a.x] * absmax);
        o[1] = (_Float16)(myl[a.y] * absmax);
        o[2] = (_Float16)(myl[a.z] * absmax);
        o[3] = (_Float16)(myl[a.w] * absmax);
        o[4] = (_Float16)(myl[b.x] * absmax);
        o[5] = (_Float16)(myl[b.y] * absmax);
        o[6] = (_Float16)(myl[b.z] * absmax);
        o[7] = (_Float16)(myl[b.w] * absmax);
        *(f16x8*)(W + (size_t)t * 8) = o;
    } else {
        size_t t = (size_t)(blockIdx.x - DEQ_BLOCKS) * 256 + threadIdx.x;
        const float4* xp = (const float4*)x;
        float4 a = xp[2 * t];
        float4 b = xp[2 * t + 1];
        f16x8 o;
        o[0] = (_Float16)a.x; o[1] = (_Float16)a.y; o[2] = (_Float16)a.z; o[3] = (_Float16)a.w;
        o[4] = (_Float16)b.x; o[5] = (_Float16)b.y; o[6] = (_Float16)b.z; o[7] = (_Float16)b.w;
        *(f16x8*)(xh + t * 8) = o;
    }
}

// ---------------- GEMM: C[M][N] = A[M][K] * B[N][K]^T ----------------
// 256x256 tile, BK=64, 512 threads = 8 waves (2M x 4N), per-wave 128x64 out
// via 8x4 frags of mfma_f32_16x16x32_f16 (2 k-steps per BK).
// This is the round-1 kernel (measured: 262 us, MfmaUtil 47%, 0 bank
// conflicts, no spill) with ONE change: XCD-contiguous block swizzle (T1).
//
// Schedule (4 phases per K-tile, proven):
//   ph1: ds_read A(m0-3)+B(n0-1) [12]; bar; lgkm0; prio1; 16 MFMA; prio0; bar
//   ph2: ds_read B(n2-3) [4];          bar; lgkm0; prio1; 16 MFMA; prio0; bar
//   ph3: ds_read A(m4-7) [8]; STAGE B(t+2) [B dead after ph2 bar];
//                                      bar; lgkm0; prio1; 16 MFMA; prio0; bar
//   ph4: STAGE A(t+2) [A dead after ph3 bar];
//        prio1; 16 MFMA; prio0; vmcnt(8); bar
// Counted vmcnt: tile t+1 (8 loads, issued iter t-1) completes at iter-t end
// while tile t+2's 8 loads stay in flight across the barrier.
//
// LDS swizzle (0-conflict, thrice-measured): 16B chunk (row r, kchunk c) ->
// physical r*8 + (c ^ (r&7)); global_load_lds dest stays lane-linear, the
// GLOBAL k-offset is pre-swizzled; reads use pos = ((kstep*4+fk) ^ (fr&7)).
//
// XCD swizzle (T1): HW round-robins consecutive blockIdx across 8 XCDs.
// d = (bid&7)*64 + (bid>>3) gives each XCD a contiguous run of 64 desired
// tiles = 4 full 4x4 super-groups -> per-XCD-L2 panel working set ~4x smaller.
// Bijective: 512 = 8*64 exactly.

__device__ __forceinline__ void async16(const _Float16* g, _Float16* l) {
    __builtin_amdgcn_global_load_lds(
        (const __attribute__((address_space(1))) void*)g,
        (__attribute__((address_space(3))) void*)l,
        16, 0, 0);
}

#define MFMA16(a, b, c) __builtin_amdgcn_mfma_f32_16x16x32_f16(a, b, c, 0, 0, 0)
#define BAR()   __builtin_amdgcn_s_barrier()
#define LGKM0() asm volatile("s_waitcnt lgkmcnt(0)" ::: "memory")

#define TILE_E (256 * 64)

__global__ __launch_bounds__(512, 2) void k_gemm(const _Float16* __restrict__ A,
                                                 const _Float16* __restrict__ B,
                                                 float* __restrict__ C) {
    const int K = IN_F, N = OUT_F;
    __shared__ __align__(1024) _Float16 sA[2][TILE_E];   // 64 KiB
    __shared__ __align__(1024) _Float16 sB[2][TILE_E];   // 64 KiB

    const int tid = threadIdx.x;
    // T1: XCD-contiguous remap, then 32 groups of 16 blocks (4 bm x 4 bn).
    const int bid = blockIdx.x;            // 0..511
    const int d   = (bid & 7) * 64 + (bid >> 3);   // desired linear tile id
    const int g   = d >> 4;                // 0..31
    const int wv  = d & 15;
    const int gy  = g >> 2;                // 0..7
    const int gx  = g & 3;                 // 0..3
    const int m0  = (gy * 4 + (wv >> 2)) * 256;
    const int n0  = (gx * 4 + (wv & 3)) * 256;

    const int lane = tid & 63;
    const int wave = tid >> 6;
    const int wm   = (wave >> 2) * 128;    // 0 or 128
    const int wn   = (wave & 3) * 64;      // 0,64,128,192

    // Fragment read addressing (16x16x32: row/col = lane&15, k-chunk = lane>>4)
    const int fr   = lane & 15;
    const int fk   = lane >> 4;
    const int sw   = fr & 7;
    const int aRow = (wm + fr) * 64;       // element offset of frag row base
    const int bRow = (wn + fr) * 64;
    const int p0   = ((0 * 4 + fk) ^ sw) * 8;   // kstep 0 phys offset (elems)
    const int p1   = ((1 * 4 + fk) ^ sw) * 8;   // kstep 1

    // Staging: pass j covers phys chunks [j*512, j*512+512): thread t -> chunk
    // j*512+t, row = j*64 + (t>>3), pos = t&7, global kchunk = pos ^ (row&7)
    // = (t&7) ^ ((t>>3)&7)  (j-invariant).
    const int rr  = tid >> 3;                              // 0..63
    const int kc  = ((tid & 7) ^ (rr & 7)) * 8;            // global k elem offset
    const _Float16* agp = A + (size_t)(m0 + rr) * K + kc;
    const _Float16* bgp = B + (size_t)(n0 + rr) * K + kc;
    const int dOff = tid * 8;                              // LDS dest elem offset base

    f32x16 acc[2][2];
    // NOTE: acc here is per 32-row pair: acc layout matches round-1 (8x4 of
    // 16x16 frags expressed as f32x4; kept as in round-1 below)
    typedef float f32x4 __attribute__((ext_vector_type(4)));
    f32x4 accv[8][4];
#pragma unroll
    for (int mi = 0; mi < 8; ++mi)
#pragma unroll
        for (int ni = 0; ni < 4; ++ni)
#pragma unroll
            for (int r = 0; r < 4; ++r) accv[mi][ni][r] = 0.f;
    (void)acc;

    // ---- prologue: stage tiles 0 (buf0) and 1 (buf1); tile1 stays in flight ----
#pragma unroll
    for (int j = 0; j < 4; ++j) async16(agp + (size_t)j * 64 * K,       &sA[0][j * 4096 + dOff]);
#pragma unroll
    for (int j = 0; j < 4; ++j) async16(bgp + (size_t)j * 64 * K,       &sB[0][j * 4096 + dOff]);
#pragma unroll
    for (int j = 0; j < 4; ++j) async16(agp + (size_t)j * 64 * K + 64,  &sA[1][j * 4096 + dOff]);
#pragma unroll
    for (int j = 0; j < 4; ++j) async16(bgp + (size_t)j * 64 * K + 64,  &sB[1][j * 4096 + dOff]);
    asm volatile("s_waitcnt vmcnt(8)" ::: "memory");   // tile0 landed, tile1 in flight
    BAR();

    const int NT = K / 64;   // 64
    f16x8 af[4][2], bf[4][2];

#pragma unroll 2
    for (int t = 0; t < NT; ++t) {
        const _Float16* sAb = sA[t & 1];
        const _Float16* sBb = sB[t & 1];
        _Float16* dA = sA[t & 1];          // tile t+2 shares this buffer
        _Float16* dB = sB[t & 1];
        const bool st = (t + 2 < NT);
        const int ktn = (t + 2) * 64;

        // ---------- phase 1: A m0-3, B n0-1 ----------
#pragma unroll
        for (int mi = 0; mi < 4; ++mi) {
            af[mi][0] = *(const f16x8*)(sAb + aRow + mi * 1024 + p0);
            af[mi][1] = *(const f16x8*)(sAb + aRow + mi * 1024 + p1);
        }
#pragma unroll
        for (int ni = 0; ni < 2; ++ni) {
            bf[ni][0] = *(const f16x8*)(sBb + bRow + ni * 1024 + p0);
            bf[ni][1] = *(const f16x8*)(sBb + bRow + ni * 1024 + p1);
        }
        BAR();
        LGKM0();
        __builtin_amdgcn_s_setprio(1);
#pragma unroll
        for (int mi = 0; mi < 4; ++mi)
#pragma unroll
            for (int ni = 0; ni < 2; ++ni) {
                accv[mi][ni] = MFMA16(af[mi][0], bf[ni][0], accv[mi][ni]);
                accv[mi][ni] = MFMA16(af[mi][1], bf[ni][1], accv[mi][ni]);
            }
        __builtin_amdgcn_s_setprio(0);
        BAR();

        // ---------- phase 2: B n2-3 ----------
#pragma unroll
        for (int ni = 2; ni < 4; ++ni) {
            bf[ni][0] = *(const f16x8*)(sBb + bRow + ni * 1024 + p0);
            bf[ni][1] = *(const f16x8*)(sBb + bRow + ni * 1024 + p1);
        }
        BAR();
        LGKM0();
        __builtin_amdgcn_s_setprio(1);
#pragma unroll
        for (int mi = 0; mi < 4; ++mi)
#pragma unroll
            for (int ni = 2; ni < 4; ++ni) {
                accv[mi][ni] = MFMA16(af[mi][0], bf[ni][0], accv[mi][ni]);
                accv[mi][ni] = MFMA16(af[mi][1], bf[ni][1], accv[mi][ni]);
            }
        __builtin_amdgcn_s_setprio(0);
        BAR();

        // ---------- phase 3: A m4-7 (reuse af regs); stage B(t+2) ----------
#pragma unroll
        for (int mi = 0; mi < 4; ++mi) {
            af[mi][0] = *(const f16x8*)(sAb + aRow + 4096 + mi * 1024 + p0);
            af[mi][1] = *(const f16x8*)(sAb + aRow + 4096 + mi * 1024 + p1);
        }
        if (st) {
#pragma unroll
            for (int j = 0; j < 4; ++j)
                async16(bgp + (size_t)j * 64 * K + ktn, &dB[j * 4096 + dOff]);
        }
        BAR();
        LGKM0();
        __builtin_amdgcn_s_setprio(1);
#pragma unroll
        for (int mi = 0; mi < 4; ++mi)
#pragma unroll
            for (int ni = 0; ni < 2; ++ni) {
                accv[mi + 4][ni] = MFMA16(af[mi][0], bf[ni][0], accv[mi + 4][ni]);
                accv[mi + 4][ni] = MFMA16(af[mi][1], bf[ni][1], accv[mi + 4][ni]);
            }
        __builtin_amdgcn_s_setprio(0);
        BAR();

        // ---------- phase 4: stage A(t+2); counted vmcnt ----------
        if (st) {
#pragma unroll
            for (int j = 0; j < 4; ++j)
                async16(agp + (size_t)j * 64 * K + ktn, &dA[j * 4096 + dOff]);
        }
        __builtin_amdgcn_s_setprio(1);
#pragma unroll
        for (int mi = 0; mi < 4; ++mi)
#pragma unroll
            for (int ni = 2; ni < 4; ++ni) {
                accv[mi + 4][ni] = MFMA16(af[mi][0], bf[ni][0], accv[mi + 4][ni]);
                accv[mi + 4][ni] = MFMA16(af[mi][1], bf[ni][1], accv[mi + 4][ni]);
            }
        __builtin_amdgcn_s_setprio(0);
        if (t < NT - 2) {
            asm volatile("s_waitcnt vmcnt(8)" ::: "memory");  // t+1 landed, t+2 in flight
        } else if (t == NT - 2) {
            asm volatile("s_waitcnt vmcnt(0)" ::: "memory");  // drain for last tile
        }
        if (t < NT - 1) BAR();
    }

    // Epilogue: 16x16x32 C/D layout col=lane&15, row=(lane>>4)*4+reg
    const int crow0 = m0 + wm + (lane >> 4) * 4;
    const int ccol0 = n0 + wn + (lane & 15);
#pragma unroll
    for (int mi = 0; mi < 8; ++mi)
#pragma unroll
        for (int ni = 0; ni < 4; ++ni)
#pragma unroll
            for (int r = 0; r < 4; ++r)
                C[(size_t)(crow0 + mi * 16 + r) * N + ccol0 + ni * 16] = accv[mi][ni][r];
}

extern "C" void kernel_launch(void* const* d_in, const int* in_sizes, int n_in,
                              void* d_out, int out_size, void* d_ws, size_t ws_size,
                              hipStream_t stream) {
    const float* x       = (const float*)d_in[0];
    const int*   indices = (const int*)d_in[1];
    const int*   qscales = (const int*)d_in[2];
    float*       out     = (float*)d_out;

    _Float16* W  = (_Float16*)d_ws;                                   // 32 MiB
    _Float16* Xh = (_Float16*)((char*)d_ws + (size_t)TOTAL_W * 2);    // 64 MiB

    k_prep<<<DEQ_BLOCKS + (int)CAST_BLOCKS, 256, 0, stream>>>(indices, qscales, W, x, Xh);
    k_gemm<<<512, 512, 0, stream>>>(Xh, W, out);
}